// Round 3
// baseline (3728.452 us; speedup 1.0000x reference)
//
#include <hip/hip_runtime.h>
#include <cstdint>

// Problem dims (fixed by reference)
#define NB    1024      // batch
#define TT    64        // time steps
#define DIN   512       // input dim
#define HD    1024      // hidden dim
#define FH    4096      // 4*H
#define KTOT  2560      // D + 2H

typedef _Float16 half8 __attribute__((ext_vector_type(8)));
typedef float floatx4 __attribute__((ext_vector_type(4)));

// ---- workspace layout (bytes). Total = 150,994,944 (144 MB) ----
#define OFF_WT    ((size_t)0)            // f16 Wt[4096][2560]          20,971,520
#define OFF_X16   ((size_t)20971520)     // f16 x[1024][64][512]        67,108,864
#define OFF_A16   ((size_t)88080384)     // f16 A[1024][1024][16]       33,554,432
#define OFF_H16   ((size_t)121634816)    // f16 h[1024][1024]            2,097,152
#define OFF_AT16  ((size_t)123731968)    // f16 attn[1024][1024]         2,097,152
#define OFF_HF    ((size_t)125829120)    // f32 h0[1024][1024]           4,194,304
#define OFF_C     ((size_t)130023424)    // f32 c[1024][1024]            4,194,304
#define OFF_ABUF  ((size_t)134217728)    // f32 a[1024][4096]           16,777,216

__device__ __forceinline__ void async_copy16(const void* g, void* l) {
    // global -> LDS direct copy, 16B/lane. LDS dest is wave-uniform base;
    // HW strides lane*16.
    __builtin_amdgcn_global_load_lds(
        (const __attribute__((address_space(1))) void*)(uintptr_t)g,
        (__attribute__((address_space(3))) void*)(uintptr_t)l,
        16, 0, 0);
}

// ---------- one-time: W = [Wx;Wh;Wattn] (2560x4096 f32) -> Wt (4096x2560 f16) ----------
__global__ void k_convert_w(const float* __restrict__ Wx, const float* __restrict__ Wh,
                            const float* __restrict__ Wattn, _Float16* __restrict__ Wt) {
    __shared__ float tile[32][33];
    const int k0 = blockIdx.x * 32;            // K in [0,2560)
    const int c0 = blockIdx.y * 32;            // out-col in [0,4096)
    const int tx = threadIdx.x & 31;
    const int ty = threadIdx.x >> 5;           // 0..7
    const float* src; int kb;
    if (k0 < 512)       { src = Wx;    kb = k0; }
    else if (k0 < 1536) { src = Wh;    kb = k0 - 512; }
    else                { src = Wattn; kb = k0 - 1536; }
    #pragma unroll
    for (int r = ty; r < 32; r += 8)
        tile[r][tx] = src[(size_t)(kb + r) * FH + c0 + tx];
    __syncthreads();
    #pragma unroll
    for (int r = ty; r < 32; r += 8)
        Wt[(size_t)(c0 + r) * KTOT + k0 + tx] = (_Float16)tile[tx][r];
}

// ---------- one-time: f32 -> f16 bulk convert (x and A) ----------
__global__ void k_convert(const float* __restrict__ src, _Float16* __restrict__ dst) {
    const size_t i = ((size_t)blockIdx.x * 256 + threadIdx.x) * 8;
    float4 v0 = *(const float4*)(src + i);
    float4 v1 = *(const float4*)(src + i + 4);
    half8 h;
    h[0] = (_Float16)v0.x; h[1] = (_Float16)v0.y; h[2] = (_Float16)v0.z; h[3] = (_Float16)v0.w;
    h[4] = (_Float16)v1.x; h[5] = (_Float16)v1.y; h[6] = (_Float16)v1.z; h[7] = (_Float16)v1.w;
    *(half8*)(dst + i) = h;
}

// ---------- one-time: h0 = c0 = mean(A over 16 cells) ----------
__global__ void k_init(const float* __restrict__ A, float* __restrict__ hf,
                       _Float16* __restrict__ h16, float* __restrict__ c) {
    const int idx = blockIdx.x * 256 + threadIdx.x;     // n*1024 + h
    const float* a = A + (size_t)idx * 16;
    float s = 0.f;
    #pragma unroll
    for (int l = 0; l < 16; l++) s += a[l];
    const float m = s * (1.0f / 16.0f);
    hf[idx] = m; h16[idx] = (_Float16)m; c[idx] = m;
}

// ---------- attention core: h values provided per-thread via hs[] LDS ----------
// block = one batch row n; 256 threads, each owns h-rows r = kk*256+tid (kk=0..3)
__device__ __forceinline__ void attn_phase(const _Float16* __restrict__ A16, int n,
                                           const float* hs /*LDS, 1024*/,
                                           float red[4][16] /*LDS*/,
                                           _Float16* __restrict__ at16) {
    const int tid = threadIdx.x, lane = tid & 63, wid = tid >> 6;
    float s[16];
    #pragma unroll
    for (int l = 0; l < 16; l++) s[l] = 0.f;
    half8 a0[4], a1[4];
    #pragma unroll
    for (int kk = 0; kk < 4; kk++) {
        const int r = kk * 256 + tid;
        const _Float16* ap = A16 + ((size_t)n * HD + r) * 16;
        a0[kk] = *(const half8*)ap;
        a1[kk] = *(const half8*)(ap + 8);
        const float hv = hs[r];
        #pragma unroll
        for (int l = 0; l < 8; l++) {
            s[l]     += hv * (float)a0[kk][l];
            s[l + 8] += hv * (float)a1[kk][l];
        }
    }
    #pragma unroll
    for (int l = 0; l < 16; l++)
        #pragma unroll
        for (int off = 32; off > 0; off >>= 1) s[l] += __shfl_down(s[l], off, 64);
    if (lane == 0) {
        #pragma unroll
        for (int l = 0; l < 16; l++) red[wid][l] = s[l];
    }
    __syncthreads();
    // every thread computes the 16-wide softmax redundantly (no serial section)
    float w[16]; float mx = -1e30f;
    #pragma unroll
    for (int l = 0; l < 16; l++) {
        w[l] = (red[0][l] + red[1][l] + red[2][l] + red[3][l]) * 0.03125f; // 1/sqrt(1024)
        mx = fmaxf(mx, w[l]);
    }
    float sum = 0.f;
    #pragma unroll
    for (int l = 0; l < 16; l++) { w[l] = __expf(w[l] - mx); sum += w[l]; }
    const float inv = 1.0f / sum;
    #pragma unroll
    for (int l = 0; l < 16; l++) w[l] *= inv;
    #pragma unroll
    for (int kk = 0; kk < 4; kk++) {
        const int r = kk * 256 + tid;
        float v = 0.f;
        #pragma unroll
        for (int l = 0; l < 8; l++) v += (float)a0[kk][l] * w[l] + (float)a1[kk][l] * w[l + 8];
        at16[(size_t)n * HD + r] = (_Float16)v;
    }
}

// ---------- t=0 bootstrap: attn from h0 (hf) ----------
__global__ void k_attn_boot(const _Float16* __restrict__ A16, const float* __restrict__ hf,
                            _Float16* __restrict__ at16) {
    __shared__ float hs[HD];
    __shared__ float red[4][16];
    const int n = blockIdx.x, tid = threadIdx.x;
    #pragma unroll
    for (int kk = 0; kk < 4; kk++) {
        const int r = kk * 256 + tid;
        hs[r] = hf[(size_t)n * HD + r];
    }
    __syncthreads();
    attn_phase(A16, n, hs, red, at16);
}

// ---------- per step: LSTM cell (t) + attention (t+1), block per batch row ----------
__global__ void k_cellattn(const float* __restrict__ abuf, const float* __restrict__ b,
                           const _Float16* __restrict__ A16,
                           float* __restrict__ c, _Float16* __restrict__ h16,
                           _Float16* __restrict__ at16, float* __restrict__ out, int t) {
    __shared__ float hs[HD];
    __shared__ float red[4][16];
    const int n = blockIdx.x, tid = threadIdx.x;
    #pragma unroll
    for (int kk = 0; kk < 4; kk++) {
        const int j = kk * 256 + tid;
        const size_t base = (size_t)n * FH + j;
        const float ai = abuf[base]        + b[j];
        const float af = abuf[base + 1024] + b[j + 1024];
        const float ao = abuf[base + 2048] + b[j + 2048];
        const float ag = abuf[base + 3072] + b[j + 3072];
        const float ig = 1.0f / (1.0f + __expf(-ai));
        const float fg = 1.0f / (1.0f + __expf(-af));
        const float og = 1.0f / (1.0f + __expf(-ao));
        const float gg = tanhf(ag);
        const int idx = n * HD + j;
        const float cn = fg * c[idx] + ig * gg;
        c[idx] = cn;
        const float hn = og * tanhf(cn);
        hs[j] = hn;
        h16[idx] = (_Float16)hn;
        out[(size_t)n * (TT * HD) + (size_t)t * HD + j] = hn;
    }
    if (t == TT - 1) return;       // uniform: no attn needed after last step
    __syncthreads();
    attn_phase(A16, n, hs, red, at16);
}

// ---------- per step: a = [x_t | h | attn] (1024x2560) * Wt^T -> 1024x4096 ----------
// 128x64 tile, 256 threads (4 waves), 48 KB LDS, 2 independent blocks/CU
// (grid 512) = 2 waves/SIMD, in-block split-K (wave (g,wm): quadrant wm,
// k-half g). NEW this round: counted-vmcnt schedule (T4) -- raw s_barrier,
// prefetch depth 2, s_waitcnt vmcnt(6) in steady state (waits only for the
// PREVIOUS tile's 6 loads; the just-issued 6 stay in flight across the
// barrier). No vmcnt(0) drain in the main loop -- removes the per-iteration
// stall __syncthreads() was forcing. sched_barrier(0) after each s_barrier
// pins compiler code motion (rule #18 / m152 discipline).
__launch_bounds__(256)
__global__ void k_gemm(const _Float16* __restrict__ xh, const _Float16* __restrict__ h16,
                       const _Float16* __restrict__ at16, const _Float16* __restrict__ Wt,
                       float* __restrict__ abuf, int t) {
    __shared__ _Float16 As[2][2][128 * 32];   // [buf][32k-slab][row][k]  32 KB
    __shared__ _Float16 Bs[2][2][64 * 32];    //                          16 KB
    const int tid  = threadIdx.x;
    const int lane = tid & 63;
    const int w    = tid >> 6;          // 0..3
    const int g    = w >> 1;            // k-half: slab g of each 64-k block
    const int wm   = w & 1;             // output row quadrant (64 rows)
    // XCD-aware decode (1D grid of 512, dispatch round-robins id%8 across
    // XCDs): each XCD covers row-panels 0..7 x an 8-col-panel band.
    const int bid = blockIdx.x;
    const int xcd = bid & 7;
    const int jj  = bid >> 3;           // 0..63
    const int bm0 = (jj & 7) * 128;                // batch rows (8 panels)
    const int bn0 = (xcd * 8 + (jj >> 3)) * 64;    // out cols (64 panels)
    const int srow = lane >> 2;         // 0..15
    const int scol = (lane & 3) * 8;    // f16 offset within 32-k slab

    auto stage = [&](int it2) {  // stage 64-k block [it2*64, it2*64+64) -> buf it2&1
        const int p  = it2 & 1;     // 6 global_load_lds per WAVE per call
        const int kb = it2 * 64;
        #pragma unroll
        for (int s = 0; s < 2; s++) {
            const int k0 = kb + s * 32;
            const _Float16* abase; int astride, klocal;
            if (k0 < DIN)           { abase = xh + (size_t)t * DIN; astride = TT * DIN; klocal = k0; }
            else if (k0 < DIN + HD) { abase = h16;  astride = HD; klocal = k0 - DIN; }
            else                    { abase = at16; astride = HD; klocal = k0 - DIN - HD; }
            #pragma unroll
            for (int q = 0; q < 2; q++) {       // A: wave w covers rows w*32+q*16
                const int row = w * 32 + q * 16;
                async_copy16(abase + (size_t)(bm0 + row + srow) * astride + klocal + scol,
                             &As[p][s][row * 32]);
            }
            // B: wave w covers rows w*16 (64 rows total)
            async_copy16(Wt + (size_t)(bn0 + w * 16 + srow) * KTOT + k0 + scol,
                         &Bs[p][s][(w * 16) * 32]);
        }
    };

    floatx4 acc[4][4];
    #pragma unroll
    for (int i = 0; i < 4; i++)
        #pragma unroll
        for (int j = 0; j < 4; j++) acc[i][j] = (floatx4)0.0f;

    // prologue: tiles 0 and 1 in flight; wait tile 0 (mine), barrier -> all
    stage(0);
    stage(1);
    asm volatile("s_waitcnt vmcnt(6)" ::: "memory");
    __builtin_amdgcn_s_barrier();
    __builtin_amdgcn_sched_barrier(0);

    const int kq = (lane >> 4) * 8;
    const int rr = lane & 15;
    const int NT = KTOT / 64;           // 40
    for (int it = 0; it < NT; it++) {
        const int p = it & 1;
        half8 af[4], bf[4];
        #pragma unroll
        for (int i = 0; i < 4; i++)
            af[i] = *(const half8*)&As[p][g][(wm * 64 + i * 16 + rr) * 32 + kq];
        #pragma unroll
        for (int j = 0; j < 4; j++)
            bf[j] = *(const half8*)&Bs[p][g][(j * 16 + rr) * 32 + kq];
        __builtin_amdgcn_s_setprio(1);
        #pragma unroll
        for (int i = 0; i < 4; i++)
            #pragma unroll
            for (int j = 0; j < 4; j++)
                acc[i][j] = __builtin_amdgcn_mfma_f32_16x16x32_f16(af[i], bf[j], acc[i][j], 0, 0, 0);
        __builtin_amdgcn_s_setprio(0);
        if (it == NT - 1) break;
        // all waves finished READING buf p (ds_reads complete before MFMA use)
        __builtin_amdgcn_s_barrier();
        __builtin_amdgcn_sched_barrier(0);
        if (it + 2 < NT) {
            stage(it + 2);              // overwrite buf p; 6 new loads in flight
            asm volatile("s_waitcnt vmcnt(6)" ::: "memory");  // tile it+1 landed (mine)
        } else {
            asm volatile("s_waitcnt vmcnt(0)" ::: "memory");  // drain final tile
        }
        __builtin_amdgcn_s_barrier();   // everyone's tile it+1 visible in LDS
        __builtin_amdgcn_sched_barrier(0);
    }

    // ---- cross-k reduction: g==1 waves hand their acc to g==0 waves ----
    __syncthreads();                 // no vmem outstanding here; full fence ok
    float* red = (float*)As;         // 32 KB overlay: [wm][i][j][lane][4]
    if (g == 1) {
        #pragma unroll
        for (int i = 0; i < 4; i++)
            #pragma unroll
            for (int j = 0; j < 4; j++)
                *(floatx4*)&red[((((wm * 4 + i) * 4 + j) * 64) + lane) * 4] = acc[i][j];
    }
    __syncthreads();
    if (g == 0) {
        #pragma unroll
        for (int i = 0; i < 4; i++)
            #pragma unroll
            for (int j = 0; j < 4; j++)
                acc[i][j] += *(const floatx4*)&red[((((wm * 4 + i) * 4 + j) * 64) + lane) * 4];
        // epilogue: C/D layout col=lane&15, row=quad*4+reg
        const int q4 = (lane >> 4) * 4;
        const int cn = lane & 15;
        #pragma unroll
        for (int i = 0; i < 4; i++)
            #pragma unroll
            for (int j = 0; j < 4; j++)
                #pragma unroll
                for (int r = 0; r < 4; r++) {
                    const int row = bm0 + wm * 64 + i * 16 + q4 + r;
                    const int col = bn0 + j * 16 + cn;
                    abuf[(size_t)row * FH + col] = acc[i][j][r];
                }
    }
}

extern "C" void kernel_launch(void* const* d_in, const int* in_sizes, int n_in,
                              void* d_out, int out_size, void* d_ws, size_t ws_size,
                              hipStream_t stream) {
    const float* x     = (const float*)d_in[0];
    const float* A     = (const float*)d_in[1];
    const float* Wx    = (const float*)d_in[2];
    const float* Wh    = (const float*)d_in[3];
    const float* Wattn = (const float*)d_in[4];
    const float* b     = (const float*)d_in[5];
    float* out = (float*)d_out;

    uint8_t* ws = (uint8_t*)d_ws;
    _Float16* Wt   = (_Float16*)(ws + OFF_WT);
    _Float16* x16  = (_Float16*)(ws + OFF_X16);
    _Float16* A16  = (_Float16*)(ws + OFF_A16);
    _Float16* h16  = (_Float16*)(ws + OFF_H16);
    _Float16* at16 = (_Float16*)(ws + OFF_AT16);
    float*    hf   = (float*)(ws + OFF_HF);
    float*    c    = (float*)(ws + OFF_C);
    float*    abuf = (float*)(ws + OFF_ABUF);

    k_convert_w<<<dim3(KTOT / 32, FH / 32), 256, 0, stream>>>(Wx, Wh, Wattn, Wt);
    k_convert<<<(NB * TT * DIN) / 2048, 256, 0, stream>>>(x, x16);
    k_convert<<<(NB * HD * 16) / 2048, 256, 0, stream>>>(A, A16);
    k_init<<<(NB * HD) / 256, 256, 0, stream>>>(A, hf, h16, c);
    k_attn_boot<<<NB, 256, 0, stream>>>(A16, hf, at16);

    for (int t = 0; t < TT; t++) {
        k_gemm<<<dim3(512), 256, 0, stream>>>(x16, h16, at16, Wt, abuf, t);
        k_cellattn<<<NB, 256, 0, stream>>>(abuf, b, A16, c, h16, at16, out, t);
    }
}

// Round 5
// 3456.473 us; speedup vs baseline: 1.0787x; 1.0787x over previous
//
#include <hip/hip_runtime.h>
#include <cstdint>

// Problem dims (fixed by reference)
#define NB    1024      // batch
#define TT    64        // time steps
#define DIN   512       // input dim
#define HD    1024      // hidden dim
#define FH    4096      // 4*H
#define KTOT  2560      // D + 2H

typedef _Float16 half8 __attribute__((ext_vector_type(8)));
typedef float floatx4 __attribute__((ext_vector_type(4)));

// ---- workspace layout (bytes). Total = 150,994,944 (144 MB) ----
#define OFF_WT    ((size_t)0)            // f16 Wt[4096][2560]          20,971,520
#define OFF_X16   ((size_t)20971520)     // f16 x[1024][64][512]        67,108,864
#define OFF_A16   ((size_t)88080384)     // f16 A[1024][1024][16]       33,554,432
#define OFF_H16   ((size_t)121634816)    // f16 h[1024][1024]            2,097,152
#define OFF_AT16  ((size_t)123731968)    // f16 attn[1024][1024]         2,097,152
#define OFF_HF    ((size_t)125829120)    // f32 h0[1024][1024]           4,194,304
#define OFF_C     ((size_t)130023424)    // f32 c[1024][1024]            4,194,304
#define OFF_ABUF  ((size_t)134217728)    // f32 a[1024][4096]           16,777,216

__device__ __forceinline__ void async_copy16(const void* g, void* l) {
    // global -> LDS direct copy, 16B/lane. LDS dest is wave-uniform base;
    // HW strides lane*16.
    __builtin_amdgcn_global_load_lds(
        (const __attribute__((address_space(1))) void*)(uintptr_t)g,
        (__attribute__((address_space(3))) void*)(uintptr_t)l,
        16, 0, 0);
}

// ---------- one-time: W = [Wx;Wh;Wattn] (2560x4096 f32) -> Wt (4096x2560 f16) ----------
__global__ void k_convert_w(const float* __restrict__ Wx, const float* __restrict__ Wh,
                            const float* __restrict__ Wattn, _Float16* __restrict__ Wt) {
    __shared__ float tile[32][33];
    const int k0 = blockIdx.x * 32;            // K in [0,2560)
    const int c0 = blockIdx.y * 32;            // out-col in [0,4096)
    const int tx = threadIdx.x & 31;
    const int ty = threadIdx.x >> 5;           // 0..7
    const float* src; int kb;
    if (k0 < 512)       { src = Wx;    kb = k0; }
    else if (k0 < 1536) { src = Wh;    kb = k0 - 512; }
    else                { src = Wattn; kb = k0 - 1536; }
    #pragma unroll
    for (int r = ty; r < 32; r += 8)
        tile[r][tx] = src[(size_t)(kb + r) * FH + c0 + tx];
    __syncthreads();
    #pragma unroll
    for (int r = ty; r < 32; r += 8)
        Wt[(size_t)(c0 + r) * KTOT + k0 + tx] = (_Float16)tile[tx][r];
}

// ---------- one-time: f32 -> f16 bulk convert (x and A) ----------
__global__ void k_convert(const float* __restrict__ src, _Float16* __restrict__ dst) {
    const size_t i = ((size_t)blockIdx.x * 256 + threadIdx.x) * 8;
    float4 v0 = *(const float4*)(src + i);
    float4 v1 = *(const float4*)(src + i + 4);
    half8 h;
    h[0] = (_Float16)v0.x; h[1] = (_Float16)v0.y; h[2] = (_Float16)v0.z; h[3] = (_Float16)v0.w;
    h[4] = (_Float16)v1.x; h[5] = (_Float16)v1.y; h[6] = (_Float16)v1.z; h[7] = (_Float16)v1.w;
    *(half8*)(dst + i) = h;
}

// ---------- one-time: h0 = c0 = mean(A over 16 cells) ----------
__global__ void k_init(const float* __restrict__ A, float* __restrict__ hf,
                       _Float16* __restrict__ h16, float* __restrict__ c) {
    const int idx = blockIdx.x * 256 + threadIdx.x;     // n*1024 + h
    const float* a = A + (size_t)idx * 16;
    float s = 0.f;
    #pragma unroll
    for (int l = 0; l < 16; l++) s += a[l];
    const float m = s * (1.0f / 16.0f);
    hf[idx] = m; h16[idx] = (_Float16)m; c[idx] = m;
}

// ---------- attention core: h values provided per-thread via hs[] LDS ----------
// block = one batch row n; 256 threads, each owns h-rows r = kk*256+tid (kk=0..3)
__device__ __forceinline__ void attn_phase(const _Float16* __restrict__ A16, int n,
                                           const float* hs /*LDS, 1024*/,
                                           float red[4][16] /*LDS*/,
                                           _Float16* __restrict__ at16) {
    const int tid = threadIdx.x, lane = tid & 63, wid = tid >> 6;
    float s[16];
    #pragma unroll
    for (int l = 0; l < 16; l++) s[l] = 0.f;
    half8 a0[4], a1[4];
    #pragma unroll
    for (int kk = 0; kk < 4; kk++) {
        const int r = kk * 256 + tid;
        const _Float16* ap = A16 + ((size_t)n * HD + r) * 16;
        a0[kk] = *(const half8*)ap;
        a1[kk] = *(const half8*)(ap + 8);
        const float hv = hs[r];
        #pragma unroll
        for (int l = 0; l < 8; l++) {
            s[l]     += hv * (float)a0[kk][l];
            s[l + 8] += hv * (float)a1[kk][l];
        }
    }
    #pragma unroll
    for (int l = 0; l < 16; l++)
        #pragma unroll
        for (int off = 32; off > 0; off >>= 1) s[l] += __shfl_down(s[l], off, 64);
    if (lane == 0) {
        #pragma unroll
        for (int l = 0; l < 16; l++) red[wid][l] = s[l];
    }
    __syncthreads();
    // every thread computes the 16-wide softmax redundantly (no serial section)
    float w[16]; float mx = -1e30f;
    #pragma unroll
    for (int l = 0; l < 16; l++) {
        w[l] = (red[0][l] + red[1][l] + red[2][l] + red[3][l]) * 0.03125f; // 1/sqrt(1024)
        mx = fmaxf(mx, w[l]);
    }
    float sum = 0.f;
    #pragma unroll
    for (int l = 0; l < 16; l++) { w[l] = __expf(w[l] - mx); sum += w[l]; }
    const float inv = 1.0f / sum;
    #pragma unroll
    for (int l = 0; l < 16; l++) w[l] *= inv;
    #pragma unroll
    for (int kk = 0; kk < 4; kk++) {
        const int r = kk * 256 + tid;
        float v = 0.f;
        #pragma unroll
        for (int l = 0; l < 8; l++) v += (float)a0[kk][l] * w[l] + (float)a1[kk][l] * w[l + 8];
        at16[(size_t)n * HD + r] = (_Float16)v;
    }
}

// ---------- t=0 bootstrap: attn from h0 (hf) ----------
__global__ void k_attn_boot(const _Float16* __restrict__ A16, const float* __restrict__ hf,
                            _Float16* __restrict__ at16) {
    __shared__ float hs[HD];
    __shared__ float red[4][16];
    const int n = blockIdx.x, tid = threadIdx.x;
    #pragma unroll
    for (int kk = 0; kk < 4; kk++) {
        const int r = kk * 256 + tid;
        hs[r] = hf[(size_t)n * HD + r];
    }
    __syncthreads();
    attn_phase(A16, n, hs, red, at16);
}

// ---------- per step: LSTM cell (t) + attention (t+1), block per batch row ----------
__global__ void k_cellattn(const float* __restrict__ abuf, const float* __restrict__ b,
                           const _Float16* __restrict__ A16,
                           float* __restrict__ c, _Float16* __restrict__ h16,
                           _Float16* __restrict__ at16, float* __restrict__ out, int t) {
    __shared__ float hs[HD];
    __shared__ float red[4][16];
    const int n = blockIdx.x, tid = threadIdx.x;
    #pragma unroll
    for (int kk = 0; kk < 4; kk++) {
        const int j = kk * 256 + tid;
        const size_t base = (size_t)n * FH + j;
        const float ai = abuf[base]        + b[j];
        const float af = abuf[base + 1024] + b[j + 1024];
        const float ao = abuf[base + 2048] + b[j + 2048];
        const float ag = abuf[base + 3072] + b[j + 3072];
        const float ig = 1.0f / (1.0f + __expf(-ai));
        const float fg = 1.0f / (1.0f + __expf(-af));
        const float og = 1.0f / (1.0f + __expf(-ao));
        const float gg = tanhf(ag);
        const int idx = n * HD + j;
        const float cn = fg * c[idx] + ig * gg;
        c[idx] = cn;
        const float hn = og * tanhf(cn);
        hs[j] = hn;
        h16[idx] = (_Float16)hn;
        out[(size_t)n * (TT * HD) + (size_t)t * HD + j] = hn;
    }
    if (t == TT - 1) return;       // uniform: no attn needed after last step
    __syncthreads();
    attn_phase(A16, n, hs, red, at16);
}

// ---------- per step: a = [x_t | h | attn] (1024x2560) * Wt^T -> 1024x4096 ----------
// 128x64 tile, 256 threads (4 waves), 2 blocks/CU (grid 512) = 2 waves/SIMD,
// in-block split-K (wave (g,wm): quadrant wm, k-half g).
// R5: asymmetric pipeline within the 64 KB static-LDS limit (R1/R4 failures
// correlate with >64KB static __shared__ -- 48KB ran twice, 72/128KB failed):
//   A stream (x|h|attn): TRIPLE buffer, flight-2. h16/at16 are re-written
//     each step by k_cellattn on other XCDs -> L2-miss (~900cy) reads; the
//     2-iteration flight (~2000cy) covers them.
//   B stream (Wt): DOUBLE buffer, flight-1. Wt band is L2-resident per XCD
//     (~200cy) -> one compute body covers it.
// Per-iter per-wave issue: stageB(it+1) [2 loads], stageA(it+2) [4 loads];
// end-of-iter s_waitcnt vmcnt(4) retires B(it+1)+A(it+1) in order while
// A(it+2)'s 4 newest stay in flight across the single s_barrier. Same
// one-barrier-per-iter skeleton as verified R2 (3516us); no sched_barrier,
// no setprio (R3 showed those regress).
// Race check: Abuf (it+2)%3 holds tile it-1 (reads done before barrier(it-1),
// enforced by lgkmcnt(0)); Bbuf (it+1)&1 holds tile it-1 likewise; stages
// are program-ordered after that barrier; vmcnt retirement is in-order.
__launch_bounds__(256)
__global__ void k_gemm(const _Float16* __restrict__ xh, const _Float16* __restrict__ h16,
                       const _Float16* __restrict__ at16, const _Float16* __restrict__ Wt,
                       float* __restrict__ abuf, int t) {
    __shared__ _Float16 As[3][2][128 * 32];   // [buf][32k-slab][row][k]  48 KB
    __shared__ _Float16 Bs[2][2][64 * 32];    //                          16 KB
    const int tid  = threadIdx.x;
    const int lane = tid & 63;
    const int w    = tid >> 6;          // 0..3
    const int g    = w >> 1;            // k-half: slab g of each 64-k block
    const int wm   = w & 1;             // output row quadrant (64 rows)
    // XCD-aware decode (1D grid of 512, dispatch round-robins id%8 across
    // XCDs): each XCD covers row-panels 0..7 x an 8-col-panel band.
    const int bid = blockIdx.x;
    const int xcd = bid & 7;
    const int jj  = bid >> 3;           // 0..63
    const int bm0 = (jj & 7) * 128;                // batch rows (8 panels)
    const int bn0 = (xcd * 8 + (jj >> 3)) * 64;    // out cols (64 panels)
    const int srow = lane >> 2;         // 0..15
    const int scol = (lane & 3) * 8;    // f16 offset within 32-k slab

    auto stageA = [&](int it2) {  // 4 global_load_lds per WAVE; buf it2%3
        const int p  = it2 % 3;
        const int kb = it2 * 64;
        #pragma unroll
        for (int s = 0; s < 2; s++) {
            const int k0 = kb + s * 32;
            const _Float16* abase; int astride, klocal;
            if (k0 < DIN)           { abase = xh + (size_t)t * DIN; astride = TT * DIN; klocal = k0; }
            else if (k0 < DIN + HD) { abase = h16;  astride = HD; klocal = k0 - DIN; }
            else                    { abase = at16; astride = HD; klocal = k0 - DIN - HD; }
            #pragma unroll
            for (int q = 0; q < 2; q++) {       // wave w covers rows w*32+q*16
                const int row = w * 32 + q * 16;
                async_copy16(abase + (size_t)(bm0 + row + srow) * astride + klocal + scol,
                             &As[p][s][row * 32]);
            }
        }
    };
    auto stageB = [&](int it2) {  // 2 global_load_lds per WAVE; buf it2&1
        const int p  = it2 & 1;
        const int kb = it2 * 64;
        #pragma unroll
        for (int s = 0; s < 2; s++) {
            const int k0 = kb + s * 32;
            // wave w covers rows w*16 (64 rows total)
            async_copy16(Wt + (size_t)(bn0 + w * 16 + srow) * KTOT + k0 + scol,
                         &Bs[p][s][(w * 16) * 32]);
        }
    };

    floatx4 acc[4][4];
    #pragma unroll
    for (int i = 0; i < 4; i++)
        #pragma unroll
        for (int j = 0; j < 4; j++) acc[i][j] = (floatx4)0.0f;

    // prologue: B(0), A(0), A(1) in flight (10 loads/wave). vmcnt(4) retires
    // the 6 oldest (B0's 2 + A0's 4); A(1)'s 4 stay in flight.
    stageB(0);
    stageA(0);
    stageA(1);
    asm volatile("s_waitcnt vmcnt(4)" ::: "memory");
    __builtin_amdgcn_s_barrier();

    const int kq = (lane >> 4) * 8;
    const int rr = lane & 15;
    const int NT = KTOT / 64;           // 40
    for (int it = 0; it < NT; it++) {
        const int pa = it % 3;
        const int pb = it & 1;
        if (it + 1 < NT) stageB(it + 1);   // into Bbuf (it+1)&1 (held tile it-1)
        if (it + 2 < NT) stageA(it + 2);   // into Abuf (it+2)%3 (held tile it-1)
        half8 af[4], bf[4];
        #pragma unroll
        for (int i = 0; i < 4; i++)
            af[i] = *(const half8*)&As[pa][g][(wm * 64 + i * 16 + rr) * 32 + kq];
        #pragma unroll
        for (int j = 0; j < 4; j++)
            bf[j] = *(const half8*)&Bs[pb][g][(j * 16 + rr) * 32 + kq];
        #pragma unroll
        for (int i = 0; i < 4; i++)
            #pragma unroll
            for (int j = 0; j < 4; j++)
                acc[i][j] = __builtin_amdgcn_mfma_f32_16x16x32_f16(af[i], bf[j], acc[i][j], 0, 0, 0);
        if (it == NT - 1) break;
        // my ds_reads of tile it completed (consumed by MFMAs above)
        asm volatile("s_waitcnt lgkmcnt(0)" ::: "memory");
        // retire A(it+1)+B(it+1) (older, in-order); A(it+2)'s 4 stay in flight
        if (it + 2 < NT) asm volatile("s_waitcnt vmcnt(4)" ::: "memory");
        else             asm volatile("s_waitcnt vmcnt(0)" ::: "memory");
        __builtin_amdgcn_s_barrier();   // everyone: tile it+1 ready, tile it reads done
    }

    // ---- cross-k reduction: g==1 waves hand their acc to g==0 waves ----
    __syncthreads();                 // vmem fully drained by tail vmcnt(0)
    float* red = (float*)As;         // 32 KB overlay: [wm][i][j][lane][4]
    if (g == 1) {
        #pragma unroll
        for (int i = 0; i < 4; i++)
            #pragma unroll
            for (int j = 0; j < 4; j++)
                *(floatx4*)&red[((((wm * 4 + i) * 4 + j) * 64) + lane) * 4] = acc[i][j];
    }
    __syncthreads();
    if (g == 0) {
        #pragma unroll
        for (int i = 0; i < 4; i++)
            #pragma unroll
            for (int j = 0; j < 4; j++)
                acc[i][j] += *(const floatx4*)&red[((((wm * 4 + i) * 4 + j) * 64) + lane) * 4];
        // epilogue: C/D layout col=lane&15, row=quad*4+reg
        const int q4 = (lane >> 4) * 4;
        const int cn = lane & 15;
        #pragma unroll
        for (int i = 0; i < 4; i++)
            #pragma unroll
            for (int j = 0; j < 4; j++)
                #pragma unroll
                for (int r = 0; r < 4; r++) {
                    const int row = bm0 + wm * 64 + i * 16 + q4 + r;
                    const int col = bn0 + j * 16 + cn;
                    abuf[(size_t)row * FH + col] = acc[i][j][r];
                }
    }
}

extern "C" void kernel_launch(void* const* d_in, const int* in_sizes, int n_in,
                              void* d_out, int out_size, void* d_ws, size_t ws_size,
                              hipStream_t stream) {
    const float* x     = (const float*)d_in[0];
    const float* A     = (const float*)d_in[1];
    const float* Wx    = (const float*)d_in[2];
    const float* Wh    = (const float*)d_in[3];
    const float* Wattn = (const float*)d_in[4];
    const float* b     = (const float*)d_in[5];
    float* out = (float*)d_out;

    uint8_t* ws = (uint8_t*)d_ws;
    _Float16* Wt   = (_Float16*)(ws + OFF_WT);
    _Float16* x16  = (_Float16*)(ws + OFF_X16);
    _Float16* A16  = (_Float16*)(ws + OFF_A16);
    _Float16* h16  = (_Float16*)(ws + OFF_H16);
    _Float16* at16 = (_Float16*)(ws + OFF_AT16);
    float*    hf   = (float*)(ws + OFF_HF);
    float*    c    = (float*)(ws + OFF_C);
    float*    abuf = (float*)(ws + OFF_ABUF);

    k_convert_w<<<dim3(KTOT / 32, FH / 32), 256, 0, stream>>>(Wx, Wh, Wattn, Wt);
    k_convert<<<(NB * TT * DIN) / 2048, 256, 0, stream>>>(x, x16);
    k_convert<<<(NB * HD * 16) / 2048, 256, 0, stream>>>(A, A16);
    k_init<<<(NB * HD) / 256, 256, 0, stream>>>(A, hf, h16, c);
    k_attn_boot<<<NB, 256, 0, stream>>>(A16, hf, at16);

    for (int t = 0; t < TT; t++) {
        k_gemm<<<dim3(512), 256, 0, stream>>>(x16, h16, at16, Wt, abuf, t);
        k_cellattn<<<NB, 256, 0, stream>>>(abuf, b, A16, c, h16, at16, out, t);
    }
}